// Round 11
// baseline (215.035 us; speedup 1.0000x reference)
//
#include <hip/hip_runtime.h>
#include <stdint.h>

#define B_ 8
#define H_ 128
#define W_ 128
#define D_ 128
#define N_ (H_*W_)
#define M_ (B_*N_)   // 131072 rows total

typedef __attribute__((ext_vector_type(8))) short short8;
typedef __attribute__((ext_vector_type(4))) float floatx4;

typedef const __attribute__((address_space(1))) void* gas_t;
typedef __attribute__((address_space(3))) void* las_t;

__device__ inline unsigned short f2bf(float f){
  union { float f; unsigned int i; } c; c.f = f;
  unsigned int x = c.i;
  x += 0x7FFF + ((x >> 16) & 1);   // RNE
  return (unsigned short)(x >> 16);
}
__device__ inline float bflo(unsigned int u){
  union { unsigned int i; float f; } c; c.i = u << 16; return c.f;
}
__device__ inline float bfhi(unsigned int u){
  union { unsigned int i; float f; } c; c.i = u & 0xFFFF0000u; return c.f;
}

// ---------------- kernel 0: W -> W^T bf16 ----------------
__global__ void wtrans_kernel(const float* __restrict__ Wq, const float* __restrict__ Wk,
                              const float* __restrict__ Wv, unsigned short* __restrict__ Wt){
  const float* src = blockIdx.x == 0 ? Wq : (blockIdx.x == 1 ? Wk : Wv);
  unsigned short* dst = Wt + blockIdx.x * (D_*D_);
  const int i = blockIdx.y * 256 + threadIdx.x;
  const int k = i >> 7, n = i & 127;
  dst[n*D_ + k] = f2bf(src[i]);
}

// ---------------- kernel 1: QKV projection — all-panels-upfront, 1 barrier ----
// The untried point after 7 pinned variants (55-62us): stage ALL THREE weight
// panels BEFORE any compute, then run the three GEMMs with ZERO inter-phase
// sync. Col-split 4-ways: block = 64 rows x 32 cols x {Q,K,V}; panels
// 3 x 32x128 bf16 = 24 KB LDS -> ~4 blocks/CU (~16 waves, vs 6 now).
// Chain/block: 6 panel-DMAs -> batched A global->reg (hides DMA; round-5/7
// proven) -> ONE __syncthreads -> 3 x {8 ds_read_b128 + 8 MFMA + 2 stores},
// pure dataflow, waves desync freely. x re-read 4x by col-group siblings is
// L2/L3 traffic (adjacent dispatch -> L2-hot), not HBM (round-6's blowup was
// cold 3x HBM re-reads — different regime).
__global__ __launch_bounds__(256, 4) void qkv_gemm_kernel(
    const float* __restrict__ x, const unsigned short* __restrict__ Wt,
    const float* __restrict__ bq, const float* __restrict__ bk, const float* __restrict__ bv,
    unsigned short* __restrict__ Q, unsigned short* __restrict__ K, unsigned short* __restrict__ V)
{
  const int cg = blockIdx.x;           // column group: output cols [cg*32, cg*32+32)
  const int rowTile = blockIdx.y;      // 64-row tile

  __shared__ unsigned short lds[12288];   // 3 panels x 32 x 128 bf16 = 24 KB

  const int t = threadIdx.x;
  const int wave = t >> 6, lane = t & 63;
  const int m0 = lane & 15, quad = lane >> 4;

  // ---- issue ALL THREE B-panel DMAs upfront (6 vm-ops/thread, no regs)
  #pragma unroll
  for (int which = 0; which < 3; ++which){
    const unsigned short* Wsel = Wt + which*(D_*D_) + cg*32*D_;   // panel: W^T rows cg*32..+32
    #pragma unroll
    for (int p = 0; p < 2; ++p){
      int s = p*256 + t;               // 16B chunk id in [0,512)
      int n = s >> 4, cp = s & 15, c = cp ^ (n & 7);
      __builtin_amdgcn_global_load_lds((gas_t)(const void*)(Wsel + n*128 + c*8),
          (las_t)(void*)((unsigned short*)lds + which*4096 + p*2048 + wave*512), 16, 0, 0);
    }
  }

  // ---- A fragments: global fp32 -> bf16 regs (batched; rounds 4/6 lesson)
  //      a[kk]: row = rowTile*64 + wave*16 + m0, k = kk*32 + quad*8 + e
  short8 a[4];
  {
    const float* xrow = x + (size_t)(rowTile*64 + wave*16 + m0) * D_ + quad*8;
    float4 f[4][2];
    #pragma unroll
    for (int kk = 0; kk < 4; ++kk){
      f[kk][0] = *(const float4*)(xrow + kk*32);
      f[kk][1] = *(const float4*)(xrow + kk*32 + 4);
    }
    __builtin_amdgcn_sched_barrier(0);   // keep the 8 loads batched
    #pragma unroll
    for (int kk = 0; kk < 4; ++kk){
      short8 v;
      v[0] = (short)f2bf(f[kk][0].x); v[1] = (short)f2bf(f[kk][0].y);
      v[2] = (short)f2bf(f[kk][0].z); v[3] = (short)f2bf(f[kk][0].w);
      v[4] = (short)f2bf(f[kk][1].x); v[5] = (short)f2bf(f[kk][1].y);
      v[6] = (short)f2bf(f[kk][1].z); v[7] = (short)f2bf(f[kk][1].w);
      a[kk] = v;
    }
  }
  __syncthreads();   // the ONLY barrier: all 3 panels landed, A in regs

  // ---- three GEMM phases, zero sync between them
  const int row = rowTile*64 + wave*16 + m0;
  #pragma unroll
  for (int which = 0; which < 3; ++which){
    // acc[j] = sum_kk mfma(b[j], a[kk]) -> lane holds C[row][col=cg*32+j*16+quad*4+r]
    floatx4 acc[2] = {};
    #pragma unroll
    for (int kk = 0; kk < 4; ++kk){
      #pragma unroll
      for (int j = 0; j < 2; ++j){
        int n = j*16 + m0;                          // panel-local W^T row (output col)
        int c = (kk*4 + quad) ^ (n & 7);
        short8 b = *(const short8*)&lds[which*4096 + n*128 + c*8];
        acc[j] = __builtin_amdgcn_mfma_f32_16x16x32_bf16(b, a[kk], acc[j], 0, 0, 0);
      }
    }
    const float* bias = which == 0 ? bq : (which == 1 ? bk : bv);
    unsigned short* Out = which == 0 ? Q : (which == 1 ? K : V);
    #pragma unroll
    for (int j = 0; j < 2; ++j){
      const int col = cg*32 + j*16 + quad*4;
      const float4 bb = *(const float4*)&bias[col];
      uint2 pk;
      pk.x = (unsigned)f2bf(acc[j][0] + bb.x) | ((unsigned)f2bf(acc[j][1] + bb.y) << 16);
      pk.y = (unsigned)f2bf(acc[j][2] + bb.z) | ((unsigned)f2bf(acc[j][3] + bb.w) << 16);
      *(uint2*)(Out + (size_t)row * D_ + col) = pk;
    }
  }
}

// ---------------- kernel 2: 3x3 window attention, 16 threads/pixel ----------------
// (byte-identical to round 10 — 184.8us best; attn no longer in top-5)
__global__ __launch_bounds__(256, 4) void attn_kernel(
    const unsigned short* __restrict__ Q, const unsigned short* __restrict__ K,
    const unsigned short* __restrict__ V, float* __restrict__ out)
{
  const int t = threadIdx.x;
  const int e16 = t & 15;                    // which 8-dim chunk
  const int pix = blockIdx.x * 16 + (t >> 4);
  const int w = pix & 127;
  const int h = (pix >> 7) & 127;
  const int bbase = pix & ~(N_ - 1);         // first pixel of this batch image
  const float scale = 0.08838834764831845f;  // 1/sqrt(128)
  const int doff = e16 * 8;
  const size_t off = (size_t)pix * D_ + doff;

  // ---- neighbor pixel indices, clamped into the image (always valid)
  int npix[9]; bool okm[9];
  #pragma unroll
  for (int i = 0; i < 9; ++i){
    const int dy = i/3 - 1, dx = i%3 - 1;
    const int hh = h + dy, ww = w + dx;
    okm[i] = ((unsigned)hh < 128u) && ((unsigned)ww < 128u);
    const int hc = min(max(hh, 0), 127);
    const int wc = min(max(ww, 0), 127);
    npix[i] = bbase + hc*W_ + wc;
  }

  // ---- q (1 uint4), then ALL 9 K loads (unconditional -> batchable)
  uint4 qu = *(const uint4*)(Q + off);
  uint4 ku[9];
  #pragma unroll
  for (int i = 0; i < 9; ++i)
    ku[i] = *(const uint4*)(K + (size_t)npix[i]*D_ + doff);

  float q[8];
  {
    unsigned uu[4] = {qu.x, qu.y, qu.z, qu.w};
    #pragma unroll
    for (int e = 0; e < 4; ++e){
      q[e*2]     = bflo(uu[e]) * scale;
      q[e*2 + 1] = bfhi(uu[e]) * scale;
    }
  }

  // ---- partial dot products (8 dims); OOB -> exact 0 via scalar select
  float s[9];
  #pragma unroll
  for (int i = 0; i < 9; ++i){
    unsigned uu[4] = {ku[i].x, ku[i].y, ku[i].z, ku[i].w};
    float acc = 0.f;
    #pragma unroll
    for (int e = 0; e < 4; ++e){
      acc += q[e*2]     * bflo(uu[e]);
      acc += q[e*2 + 1] * bfhi(uu[e]);
    }
    s[i] = okm[i] ? acc : 0.f;
  }

  // ---- issue ALL 9 V loads now; they fly under the reduce + softmax
  uint4 vu[9];
  #pragma unroll
  for (int i = 0; i < 9; ++i)
    vu[i] = *(const uint4*)(V + (size_t)npix[i]*D_ + doff);

  // 16-lane reduce (all 16 lanes of a pixel share okm -> select-then-reduce ok)
  #pragma unroll
  for (int i = 0; i < 9; ++i){
    s[i] += __shfl_xor(s[i], 1, 64);
    s[i] += __shfl_xor(s[i], 2, 64);
    s[i] += __shfl_xor(s[i], 4, 64);
    s[i] += __shfl_xor(s[i], 8, 64);
  }

  // ---- softmax (OOB score is exactly 0, participates — ref zero-pad semantics)
  float m = s[0];
  #pragma unroll
  for (int i = 1; i < 9; ++i) m = fmaxf(m, s[i]);
  float l = 0.f;
  float p[9];
  #pragma unroll
  for (int i = 0; i < 9; ++i){ p[i] = __expf(s[i] - m); l += p[i]; }
  const float inv = 1.f / l;

  // ---- PV accumulate; OOB contributes 0 via select on pi
  float o[8];
  #pragma unroll
  for (int d = 0; d < 8; ++d) o[d] = 0.f;
  #pragma unroll
  for (int i = 0; i < 9; ++i){
    const float pi = okm[i] ? p[i] * inv : 0.f;
    unsigned uu[4] = {vu[i].x, vu[i].y, vu[i].z, vu[i].w};
    #pragma unroll
    for (int e = 0; e < 4; ++e){
      o[e*2]     += pi * bflo(uu[e]);
      o[e*2 + 1] += pi * bfhi(uu[e]);
    }
  }

  float* op = out + off;
  *(float4*)op       = make_float4(o[0], o[1], o[2], o[3]);
  *(float4*)(op + 4) = make_float4(o[4], o[5], o[6], o[7]);
}

extern "C" void kernel_launch(void* const* d_in, const int* in_sizes, int n_in,
                              void* d_out, int out_size, void* d_ws, size_t ws_size,
                              hipStream_t stream)
{
  const float* x  = (const float*)d_in[0];
  const float* Wq = (const float*)d_in[1];
  const float* bq = (const float*)d_in[2];
  const float* Wk = (const float*)d_in[3];
  const float* bk = (const float*)d_in[4];
  const float* Wv = (const float*)d_in[5];
  const float* bv = (const float*)d_in[6];
  float* out = (float*)d_out;

  char* ws = (char*)d_ws;
  unsigned short* Wt = (unsigned short*)ws;                                   // 96 KB
  unsigned short* Q  = (unsigned short*)(ws + (1<<17));
  unsigned short* K  = (unsigned short*)(ws + (1<<17) + (size_t)M_*D_*2);
  unsigned short* V  = (unsigned short*)(ws + (1<<17) + (size_t)2*M_*D_*2);   // ~96.1 MB

  hipLaunchKernelGGL(wtrans_kernel, dim3(3, 64), dim3(256), 0, stream, Wq, Wk, Wv, Wt);
  hipLaunchKernelGGL(qkv_gemm_kernel, dim3(4, M_/64), dim3(256), 0, stream,
                     x, Wt, bq, bk, bv, Q, K, V);
  hipLaunchKernelGGL(attn_kernel, dim3(M_/16), dim3(256), 0, stream, Q, K, V, out);
}